// Round 9
// baseline (171.712 us; speedup 1.0000x reference)
//
#include <hip/hip_runtime.h>

namespace {

typedef _Float16 v8h __attribute__((ext_vector_type(8)));
typedef float    v4f __attribute__((ext_vector_type(4)));

constexpr int NMEL = 128;
constexpr int ND   = 64;
constexpr int NK   = 128;
constexpr int NTOK = 32 * 4096;          // 131072
constexpr int TPB  = 64;                 // tokens per block (4 waves x 16)
constexpr int GRID = NTOK / TPB;         // 2048 = 8 blocks/CU of work

// ---------------------------------------------------------------------------
// precomp: all token-independent tables into d_ws.
//   E[j][m] = sum_d cb01[j][d]*w_in[d][m] -> f16 hi/lo, stored SWIZZLED in
//   MFMA-fragment order: per (stage s, c-block c): 8KB = [hi kk0..3][lo kk0..3]
//   of 1KB each; element lane*16B + e*2B holds
//   E[s*128 + c*16 + (lane&15)][kk*32 + (lane>>4)*8 + e].
//   nh[j] = 0.5||c_j||^2 - b_in.c_j ; G[a][b] = cb0_a.cb1_b ;
//   Dec0[a][m] = cb0_a.w_out_m + b_out_m ; Dec1[b][m] = cb1_b.w_out_m.
// ---------------------------------------------------------------------------
__global__ __launch_bounds__(256) void precomp(
    const float* __restrict__ w_in, const float* __restrict__ b_in,
    const float* __restrict__ cb0, const float* __restrict__ cb1,
    const float* __restrict__ w_out, const float* __restrict__ b_out,
    float* __restrict__ dec0, float* __restrict__ dec1,
    float* __restrict__ G, float* __restrict__ nh,
    _Float16* __restrict__ E_swz) {
  const int j = blockIdx.x;          // 0..255
  const int tid = threadIdx.x;
  const float* __restrict__ crow = (j < NK) ? (cb0 + j * ND) : (cb1 + (j - NK) * ND);

  if (tid < NMEL) {
    const int m = tid;
    float e = 0.f;
#pragma unroll 8
    for (int d = 0; d < ND; ++d) e += crow[d] * w_in[d * NMEL + m];
    const _Float16 hi = (_Float16)e;
    const _Float16 lo = (_Float16)(e - (float)hi);
    const int s = j >> 7, jj = j & 127, c = jj >> 4, mr = jj & 15;
    const int kk = m >> 5, q = (m >> 3) & 3, ei = m & 7;
    const int lane = q * 16 + mr;
    const size_t base = ((((size_t)s * 8 + c) * 8) + kk) * 512;  // h=0 chunk (halves)
    E_swz[base + lane * 8 + ei] = hi;
    E_swz[base + 2048 + lane * 8 + ei] = lo;                     // h=1 chunk
  } else {
    const int m = tid - NMEL;
    const float4* wr = (const float4*)(w_out + m * ND);
    const float4* cr4 = (const float4*)crow;
    float a = 0.f;
#pragma unroll
    for (int qq = 0; qq < ND / 4; ++qq) {
      const float4 w4 = wr[qq], c4 = cr4[qq];
      a += c4.x * w4.x + c4.y * w4.y + c4.z * w4.z + c4.w * w4.w;
    }
    if (j < NK) dec0[j * NMEL + m] = a + b_out[m];
    else        dec1[(j - NK) * NMEL + m] = a;
    if (j < NK) {
      const float4* c1r = (const float4*)(cb1 + m * ND);
      float g = 0.f;
#pragma unroll
      for (int qq = 0; qq < ND / 4; ++qq) {
        const float4 c4 = cr4[qq], d4 = c1r[qq];
        g += c4.x * d4.x + c4.y * d4.y + c4.z * d4.z + c4.w * d4.w;
      }
      G[j * NK + m] = g;
    }
  }
  if (tid < 64) {  // whole first wave: nh[j] via butterfly reduce
    const float v = crow[tid];
    float t = 0.5f * v * v - b_in[tid] * v;
#pragma unroll
    for (int d = 1; d < 64; d <<= 1) t += __shfl_xor(t, d);
    if (tid == 0) nh[j] = t;
  }
}

// ---------------------------------------------------------------------------
// main: r8 kernel verbatim EXCEPT the occupancy attribute.
// r8 evidence: VGPR=76, LDS=32KB -> resources allow 5 blocks/CU (20 waves)
// but (256,2) builds all sit at ~2 waves/SIMD: launch_bounds min-waves=2
// lets the allocator claim the full 2-wave budget. Naming >=4 via
// launch_bounds overshot to the 64-reg tier and spilled (r1/r2/r3, kernels
// needing ~124 regs). This kernel needs 76, so pin a waves WINDOW:
// amdgpu_waves_per_eu(4,6) -> budget in [85,128] (76 fits, NO spill; max 6
// forbids the 64-reg tier). Expected residency: 5 blocks/CU (LDS-capped).
// ---------------------------------------------------------------------------
__global__
__attribute__((amdgpu_flat_work_group_size(256, 256), amdgpu_waves_per_eu(4, 6)))
void rvq_main(
    const float* __restrict__ mel,
    const _Float16* __restrict__ E_swz,
    const float* __restrict__ nh,
    const float* __restrict__ G,
    const float* __restrict__ dec0,
    const float* __restrict__ dec1,
    float* __restrict__ out) {
  __shared__ _Float16 sE[2][8192];   // 2 x 16 KB chunk buffers
  const int tid = threadIdx.x;
  const int wv = tid >> 6;
  const int ln = tid & 63;
  const int m  = ln & 15;
  const int q  = ln >> 4;

  // fill chunk ch (16 KB = c-blocks {2ch, 2ch+1} of E, hi+lo) into sE[ch&1]
  auto FILL = [&](int ch) {
    const char* g = (const char*)E_swz + (size_t)ch * 16384;
    char* l = (char*)(&sE[ch & 1][0]);
#pragma unroll
    for (int it = 0; it < 4; ++it) {
      __builtin_amdgcn_global_load_lds(
          (const __attribute__((address_space(1))) void*)(g + it * 4096 + wv * 1024 + ln * 16),
          (__attribute__((address_space(3))) void*)(l + it * 4096 + wv * 1024),
          16, 0, 0);
    }
  };

  FILL(0);

  // ---- A fragments: 1 tile x 16 tokens, fp32 -> f16 hi+lo (hides fill0) --
  v8h a_hi[4], a_lo[4];
  {
    const int tok0 = blockIdx.x * TPB + wv * 16;
    const float* xr = mel + (size_t)(tok0 + m) * NMEL + q * 8;
#pragma unroll
    for (int kk = 0; kk < 4; ++kk) {
      const float4 x0 = *(const float4*)(xr + kk * 32);
      const float4 x1 = *(const float4*)(xr + kk * 32 + 4);
      const float xs[8] = {x0.x, x0.y, x0.z, x0.w, x1.x, x1.y, x1.z, x1.w};
#pragma unroll
      for (int e = 0; e < 8; ++e) {
        const _Float16 h = (_Float16)xs[e];
        a_hi[kk][e] = h;
        a_lo[kk][e] = (_Float16)(xs[e] - (float)h);
      }
    }
  }

  float nhv[8];
#pragma unroll
  for (int c = 0; c < 8; ++c) nhv[c] = nh[c * 16 + m];

  float bv[4];
  int   bi[4];
  int   s0i[4], s1i[4];
  float gc[4];

  // one 2-c compute step from chunk buffer ch&1. cbase = (ch&3)*2.
  auto COMP = [&](int ch, bool stage1) {
    const _Float16* __restrict__ buf = &sE[ch & 1][0];
    const int cbase = (ch & 3) * 2;
#pragma unroll
    for (int cc = 0; cc < 2; ++cc) {
      const int c = cbase + cc;
      v8h bh[4], bl[4];
#pragma unroll
      for (int kk = 0; kk < 4; ++kk) {
        bh[kk] = *(const v8h*)(buf + cc * 4096 + kk * 512 + ln * 8);
        bl[kk] = *(const v8h*)(buf + cc * 4096 + 2048 + kk * 512 + ln * 8);
      }
      float gn[4];
      if (stage1 && c < 7) {
#pragma unroll
        for (int i = 0; i < 4; ++i)
          gn[i] = G[(size_t)s0i[i] * NK + (c + 1) * 16 + m];
      }
      v4f a0 = (v4f){0.f, 0.f, 0.f, 0.f};
#pragma unroll
      for (int kk = 0; kk < 4; ++kk) {
        a0 = __builtin_amdgcn_mfma_f32_16x16x32_f16(a_hi[kk], bh[kk], a0, 0, 0, 0);
        a0 = __builtin_amdgcn_mfma_f32_16x16x32_f16(a_lo[kk], bh[kk], a0, 0, 0, 0);
        a0 = __builtin_amdgcn_mfma_f32_16x16x32_f16(a_hi[kk], bl[kk], a0, 0, 0, 0);
      }
      const float nv = nhv[c];
      const int jj = c * 16 + m;
      if (!stage1) {
#pragma unroll
        for (int i = 0; i < 4; ++i) {
          const float s0 = nv - a0[i];
          if (s0 < bv[i]) { bv[i] = s0; bi[i] = jj; }
        }
      } else {
#pragma unroll
        for (int i = 0; i < 4; ++i) {
          const float s0 = nv + gc[i] - a0[i];
          if (s0 < bv[i]) { bv[i] = s0; bi[i] = jj; }
        }
        if (c < 7) {
#pragma unroll
          for (int i = 0; i < 4; ++i) gc[i] = gn[i];
        }
      }
    }
  };

  auto REDUCE = [&](int (&dst)[4]) {
#pragma unroll
    for (int d = 1; d < 16; d <<= 1)
#pragma unroll
      for (int i = 0; i < 4; ++i) {
        const float ov = __shfl_xor(bv[i], d);
        const int   oi = __shfl_xor(bi[i], d);
        if (ov < bv[i] || (ov == bv[i] && oi < bi[i])) { bv[i] = ov; bi[i] = oi; }
      }
#pragma unroll
    for (int i = 0; i < 4; ++i) dst[i] = bi[i];
  };

#pragma unroll
  for (int i = 0; i < 4; ++i) { bv[i] = 3.4e38f; bi[i] = 0; }

  __syncthreads();                 // fill0 done

  // ---- stage 0: chunks 0..3 (c = 0..7) ----
  FILL(1); COMP(0, false); __syncthreads();
  FILL(2); COMP(1, false); __syncthreads();
  FILL(3); COMP(2, false); __syncthreads();
  FILL(4); COMP(3, false);
  REDUCE(s0i);
  __syncthreads();                 // fill4 done; buf[1] free

  // ---- stage-1 constants; chunks 4..7 (c = 0..7 of stage 1) ----
#pragma unroll
  for (int c = 0; c < 8; ++c) nhv[c] = nh[NK + c * 16 + m];
#pragma unroll
  for (int i = 0; i < 4; ++i) {
    gc[i] = G[(size_t)s0i[i] * NK + m];  // c=0
    bv[i] = 3.4e38f; bi[i] = 0;
  }

  FILL(5); COMP(4, true); __syncthreads();
  FILL(6); COMP(5, true); __syncthreads();
  FILL(7); COMP(6, true); __syncthreads();
  COMP(7, true);                   // last chunk: no fill, no sync
  REDUCE(s1i);

  // ---- epilogue: out = Dec0[s0] + Dec1[s1] ----
#pragma unroll
  for (int i = 0; i < 4; ++i) {
    const int tok = blockIdx.x * TPB + wv * 16 + q * 4 + i;
    const float4* p0 = (const float4*)(dec0 + (size_t)s0i[i] * NMEL + m * 8);
    const float4* p1 = (const float4*)(dec1 + (size_t)s1i[i] * NMEL + m * 8);
    float4* o = (float4*)(out + (size_t)tok * NMEL + m * 8);
    const float4 u0 = p0[0], u1 = p0[1], w0 = p1[0], w1 = p1[1];
    float4 r0, r1;
    r0.x = u0.x + w0.x; r0.y = u0.y + w0.y; r0.z = u0.z + w0.z; r0.w = u0.w + w0.w;
    r1.x = u1.x + w1.x; r1.y = u1.y + w1.y; r1.z = u1.z + w1.z; r1.w = u1.w + w1.w;
    o[0] = r0; o[1] = r1;
  }
}

}  // namespace

extern "C" void kernel_launch(void* const* d_in, const int* in_sizes, int n_in,
                              void* d_out, int out_size, void* d_ws, size_t ws_size,
                              hipStream_t stream) {
  const float* mel   = (const float*)d_in[0];
  const float* w_in  = (const float*)d_in[1];
  const float* b_in  = (const float*)d_in[2];
  const float* cb0   = (const float*)d_in[3];
  const float* cb1   = (const float*)d_in[4];
  const float* w_out = (const float*)d_in[5];
  const float* b_out = (const float*)d_in[6];
  float* out = (float*)d_out;

  // ws: dec0 | dec1 | G | nh | E_swz  (64+64+64+1+128 KB ~ 321 KB)
  float* dec0 = (float*)d_ws;
  float* dec1 = dec0 + NK * NMEL;
  float* G    = dec1 + NK * NMEL;
  float* nh   = G + NK * NK;
  _Float16* E_swz = (_Float16*)(nh + 2 * NK);

  hipLaunchKernelGGL(precomp, dim3(2 * NK), dim3(256), 0, stream,
                     w_in, b_in, cb0, cb1, w_out, b_out, dec0, dec1, G, nh, E_swz);
  hipLaunchKernelGGL(rvq_main, dim3(GRID), dim3(256), 0, stream,
                     mel, E_swz, nh, G, dec0, dec1, out);
}

// Round 10
// 160.264 us; speedup vs baseline: 1.0714x; 1.0714x over previous
//
#include <hip/hip_runtime.h>

namespace {

typedef _Float16 v8h __attribute__((ext_vector_type(8)));
typedef float    v4f __attribute__((ext_vector_type(4)));

constexpr int NMEL = 128;
constexpr int ND   = 64;
constexpr int NK   = 128;
constexpr int NTOK = 32 * 4096;          // 131072
constexpr int TPB  = 64;                 // tokens per block (4 waves x 16)
constexpr int GRID = NTOK / TPB;         // 2048 = 8 blocks/CU of work

// ---------------------------------------------------------------------------
// precomp: all token-independent tables into d_ws.
//   E[j][m] = sum_d cb01[j][d]*w_in[d][m] -> f16 hi/lo, stored SWIZZLED in
//   MFMA-fragment order: per (stage s, c-block c): 8KB = [hi kk0..3][lo kk0..3]
//   of 1KB each; element lane*16B + e*2B holds
//   E[s*128 + c*16 + (lane&15)][kk*32 + (lane>>4)*8 + e].
//   nh[j] = 0.5||c_j||^2 - b_in.c_j ; G[a][b] = cb0_a.cb1_b ;
//   Dec0[a][m] = cb0_a.w_out_m + b_out_m ; Dec1[b][m] = cb1_b.w_out_m.
// ---------------------------------------------------------------------------
__global__ __launch_bounds__(256) void precomp(
    const float* __restrict__ w_in, const float* __restrict__ b_in,
    const float* __restrict__ cb0, const float* __restrict__ cb1,
    const float* __restrict__ w_out, const float* __restrict__ b_out,
    float* __restrict__ dec0, float* __restrict__ dec1,
    float* __restrict__ G, float* __restrict__ nh,
    _Float16* __restrict__ E_swz) {
  const int j = blockIdx.x;          // 0..255
  const int tid = threadIdx.x;
  const float* __restrict__ crow = (j < NK) ? (cb0 + j * ND) : (cb1 + (j - NK) * ND);

  if (tid < NMEL) {
    const int m = tid;
    float e = 0.f;
#pragma unroll 8
    for (int d = 0; d < ND; ++d) e += crow[d] * w_in[d * NMEL + m];
    const _Float16 hi = (_Float16)e;
    const _Float16 lo = (_Float16)(e - (float)hi);
    const int s = j >> 7, jj = j & 127, c = jj >> 4, mr = jj & 15;
    const int kk = m >> 5, q = (m >> 3) & 3, ei = m & 7;
    const int lane = q * 16 + mr;
    const size_t base = ((((size_t)s * 8 + c) * 8) + kk) * 512;  // h=0 chunk (halves)
    E_swz[base + lane * 8 + ei] = hi;
    E_swz[base + 2048 + lane * 8 + ei] = lo;                     // h=1 chunk
  } else {
    const int m = tid - NMEL;
    const float4* wr = (const float4*)(w_out + m * ND);
    const float4* cr4 = (const float4*)crow;
    float a = 0.f;
#pragma unroll
    for (int qq = 0; qq < ND / 4; ++qq) {
      const float4 w4 = wr[qq], c4 = cr4[qq];
      a += c4.x * w4.x + c4.y * w4.y + c4.z * w4.z + c4.w * w4.w;
    }
    if (j < NK) dec0[j * NMEL + m] = a + b_out[m];
    else        dec1[(j - NK) * NMEL + m] = a;
    if (j < NK) {
      const float4* c1r = (const float4*)(cb1 + m * ND);
      float g = 0.f;
#pragma unroll
      for (int qq = 0; qq < ND / 4; ++qq) {
        const float4 c4 = cr4[qq], d4 = c1r[qq];
        g += c4.x * d4.x + c4.y * d4.y + c4.z * d4.z + c4.w * d4.w;
      }
      G[j * NK + m] = g;
    }
  }
  if (tid < 64) {  // whole first wave: nh[j] via butterfly reduce
    const float v = crow[tid];
    float t = 0.5f * v * v - b_in[tid] * v;
#pragma unroll
    for (int d = 1; d < 64; d <<= 1) t += __shfl_xor(t, d);
    if (tid == 0) nh[j] = t;
  }
}

// ---------------------------------------------------------------------------
// main: 64-VGPR-diet build. Tier model from r0-r9: wave-slot tiers are
// {64,128,256} regs; any attr asking >4 waves/EU forces the 64 budget;
// (256,2) grants 256 (-> 2 waves/SIMD always). Only spill-free path above
// 2 waves/SIMD: usage <= 64. Diet vs r8 (76 regs):
//   - a_lo fragments in LDS (lane-private, 1 extra ds_read_b128/kk)  -16
//   - B loaded per-kk (transient 8-16 instead of 32)                 -16
//   - nv/gcv loaded per c-block (no nhv[8]/gc-gn chain)              -12
// LDS: 2x8KB E dbuf (1-c chunks, 16 steps) + 16KB a_lo = 32KB -> 5 blk/CU.
// Plain launch_bounds(256): allocator's 64-tier preference is now desired.
// ---------------------------------------------------------------------------
__global__ __launch_bounds__(256) void rvq_main(
    const float* __restrict__ mel,
    const _Float16* __restrict__ E_swz,
    const float* __restrict__ nh,
    const float* __restrict__ G,
    const float* __restrict__ dec0,
    const float* __restrict__ dec1,
    float* __restrict__ out) {
  __shared__ _Float16 sE[16384];   // [0,8192): E dbuf (2x4096h); [8192,16384): a_lo
  const int tid = threadIdx.x;
  const int wv = tid >> 6;
  const int ln = tid & 63;
  const int m  = ln & 15;
  const int q  = ln >> 4;

  // fill chunk ch (8 KB = c-block ch&7 of stage ch>>3, hi+lo) into buf ch&1
  auto FILL = [&](int ch) {
    const char* g = (const char*)E_swz + (size_t)ch * 8192;
    char* l = (char*)(sE + (ch & 1) * 4096);
#pragma unroll
    for (int it = 0; it < 2; ++it) {
      __builtin_amdgcn_global_load_lds(
          (const __attribute__((address_space(1))) void*)(g + it * 4096 + tid * 16),
          (__attribute__((address_space(3))) void*)(l + it * 4096 + tid * 16),
          16, 0, 0);
    }
  };

  FILL(0);

  // ---- A fragments: a_hi in regs, a_lo into lane-private LDS (hides fill0)
  v8h a_hi[4];
  _Float16* const aLo = sE + 8192 + wv * 2048;   // 4KB/wave region
  {
    const int tok0 = blockIdx.x * TPB + wv * 16;
    const float* xr = mel + (size_t)(tok0 + m) * NMEL + q * 8;
#pragma unroll
    for (int kk = 0; kk < 4; ++kk) {
      const float4 x0 = *(const float4*)(xr + kk * 32);
      const float4 x1 = *(const float4*)(xr + kk * 32 + 4);
      const float xs[8] = {x0.x, x0.y, x0.z, x0.w, x1.x, x1.y, x1.z, x1.w};
      v8h al;
#pragma unroll
      for (int e = 0; e < 8; ++e) {
        const _Float16 h = (_Float16)xs[e];
        a_hi[kk][e] = h;
        al[e] = (_Float16)(xs[e] - (float)h);
      }
      *(v8h*)(aLo + kk * 512 + ln * 8) = al;   // same fragment pattern as E
    }
  }

  float bv[4];
  int   bi[4];
  int   s0i[4], s1i[4];

  // one c-block compute from buf ch&1. nv/gcv issued first, used after MFMAs.
  auto COMP = [&](int ch, bool stage1) {
    const _Float16* __restrict__ buf = sE + (ch & 1) * 4096;
    const int c = ch & 7;
    const float nv = nh[(stage1 ? NK : 0) + c * 16 + m];
    float gcv[4];
    if (stage1) {
#pragma unroll
      for (int i = 0; i < 4; ++i)
        gcv[i] = G[(size_t)s0i[i] * NK + c * 16 + m];
    }
    v4f a0 = (v4f){0.f, 0.f, 0.f, 0.f};
#pragma unroll
    for (int kk = 0; kk < 4; ++kk) {
      const v8h bh = *(const v8h*)(buf + kk * 512 + ln * 8);
      const v8h bl = *(const v8h*)(buf + 2048 + kk * 512 + ln * 8);
      const v8h al = *(const v8h*)(aLo + kk * 512 + ln * 8);
      a0 = __builtin_amdgcn_mfma_f32_16x16x32_f16(a_hi[kk], bh, a0, 0, 0, 0);
      a0 = __builtin_amdgcn_mfma_f32_16x16x32_f16(al,       bh, a0, 0, 0, 0);
      a0 = __builtin_amdgcn_mfma_f32_16x16x32_f16(a_hi[kk], bl, a0, 0, 0, 0);
    }
    const int jj = c * 16 + m;
    if (!stage1) {
#pragma unroll
      for (int i = 0; i < 4; ++i) {
        const float s0 = nv - a0[i];
        if (s0 < bv[i]) { bv[i] = s0; bi[i] = jj; }
      }
    } else {
#pragma unroll
      for (int i = 0; i < 4; ++i) {
        const float s0 = nv + gcv[i] - a0[i];
        if (s0 < bv[i]) { bv[i] = s0; bi[i] = jj; }
      }
    }
  };

  auto REDUCE = [&](int (&dst)[4]) {
#pragma unroll
    for (int d = 1; d < 16; d <<= 1)
#pragma unroll
      for (int i = 0; i < 4; ++i) {
        const float ov = __shfl_xor(bv[i], d);
        const int   oi = __shfl_xor(bi[i], d);
        if (ov < bv[i] || (ov == bv[i] && oi < bi[i])) { bv[i] = ov; bi[i] = oi; }
      }
#pragma unroll
    for (int i = 0; i < 4; ++i) dst[i] = bi[i];
  };

#pragma unroll
  for (int i = 0; i < 4; ++i) { bv[i] = 3.4e38f; bi[i] = 0; }

  __syncthreads();                 // fill0 complete (a_lo is lane-private)

  // ---- 16 c-steps: fill(ch+1) overlaps comp(ch); barrier recycles buffers.
#pragma unroll
  for (int ch = 0; ch < 16; ++ch) {
    if (ch < 15) FILL(ch + 1);
    COMP(ch, ch >= 8);
    if (ch == 7) {                 // stage boundary
      REDUCE(s0i);
#pragma unroll
      for (int i = 0; i < 4; ++i) { bv[i] = 3.4e38f; bi[i] = 0; }
    }
    if (ch < 15) __syncthreads();  // fill(ch+1) done; all waves off buf ch&1
  }
  REDUCE(s1i);

  // ---- epilogue: out = Dec0[s0] + Dec1[s1] ----
#pragma unroll
  for (int i = 0; i < 4; ++i) {
    const int tok = blockIdx.x * TPB + wv * 16 + q * 4 + i;
    const float4* p0 = (const float4*)(dec0 + (size_t)s0i[i] * NMEL + m * 8);
    const float4* p1 = (const float4*)(dec1 + (size_t)s1i[i] * NMEL + m * 8);
    float4* o = (float4*)(out + (size_t)tok * NMEL + m * 8);
    const float4 u0 = p0[0], u1 = p0[1], w0 = p1[0], w1 = p1[1];
    float4 r0, r1;
    r0.x = u0.x + w0.x; r0.y = u0.y + w0.y; r0.z = u0.z + w0.z; r0.w = u0.w + w0.w;
    r1.x = u1.x + w1.x; r1.y = u1.y + w1.y; r1.z = u1.z + w1.z; r1.w = u1.w + w1.w;
    o[0] = r0; o[1] = r1;
  }
}

}  // namespace

extern "C" void kernel_launch(void* const* d_in, const int* in_sizes, int n_in,
                              void* d_out, int out_size, void* d_ws, size_t ws_size,
                              hipStream_t stream) {
  const float* mel   = (const float*)d_in[0];
  const float* w_in  = (const float*)d_in[1];
  const float* b_in  = (const float*)d_in[2];
  const float* cb0   = (const float*)d_in[3];
  const float* cb1   = (const float*)d_in[4];
  const float* w_out = (const float*)d_in[5];
  const float* b_out = (const float*)d_in[6];
  float* out = (float*)d_out;

  // ws: dec0 | dec1 | G | nh | E_swz  (64+64+64+1+128 KB ~ 321 KB)
  float* dec0 = (float*)d_ws;
  float* dec1 = dec0 + NK * NMEL;
  float* G    = dec1 + NK * NMEL;
  float* nh   = G + NK * NK;
  _Float16* E_swz = (_Float16*)(nh + 2 * NK);

  hipLaunchKernelGGL(precomp, dim3(2 * NK), dim3(256), 0, stream,
                     w_in, b_in, cb0, cb1, w_out, b_out, dec0, dec1, G, nh, E_swz);
  hipLaunchKernelGGL(rvq_main, dim3(GRID), dim3(256), 0, stream,
                     mel, E_swz, nh, G, dec0, dec1, out);
}